// Round 11
// baseline (159.579 us; speedup 1.0000x reference)
//
#include <hip/hip_runtime.h>
#include <math.h>

#define NRAYS 8192

typedef short bf16x8 __attribute__((ext_vector_type(8)));
typedef float f32x4  __attribute__((ext_vector_type(4)));

__device__ __host__ __forceinline__ unsigned short f2bf(float f) {
    union { float f; unsigned u; } v; v.f = f;
    unsigned r = v.u + 0x7FFFu + ((v.u >> 16) & 1u);
    return (unsigned short)(r >> 16);
}
// packed bf16 convert: dst = {bf16(a) lo, bf16(b) hi} — 1 instr vs 7
__device__ __forceinline__ unsigned cvtpk(float a, float b) {
    unsigned r;
    __asm__("v_cvt_pk_bf16_f32 %0, %1, %2" : "=v"(r) : "v"(a), "v"(b));
    return r;
}
__device__ __forceinline__ float fastrcp(float x) {
    float r;
    __asm__("v_rcp_f32 %0, %1" : "=v"(r) : "v"(x));
    return r;
}

// ---------------- prep: pack w0/w1/w2 into MFMA B-fragment order ----------------
// Frag f<16: L0 (ks=f>>3, nt=f&7), K=64, rows>=39 zero. 16..47: L1.
// 48..51: L2 w2 (128,3) as one 16-col tile (ks=f-48), cols>=3 zero.
// Lane l holds B[k=(l>>4)*8+j][n], 8 bf16 = 16 B.
__global__ void prep_weights(const float* __restrict__ w0,
                             const float* __restrict__ w1,
                             const float* __restrict__ w2,
                             uint4* __restrict__ wsB)
{
    const int f = blockIdx.x;   // 0..51
    const int l = threadIdx.x;  // 0..63
    const int n = l & 15;
    unsigned p[4];
    if (f < 48) {
        const float* W; int kvalid, ks, nt;
        if (f < 16) { ks = f >> 3; nt = f & 7; W = w0; kvalid = 39; }
        else        { int g = f - 16; ks = g >> 3; nt = g & 7; W = w1; kvalid = 128; }
        const int nn = nt * 16 + n;
        const int kb = ks * 32 + ((l >> 4) << 3);
        #pragma unroll
        for (int w = 0; w < 4; ++w) {
            int k0i = kb + 2 * w;
            float v0 = (k0i     < kvalid) ? W[(size_t)k0i * 128 + nn]       : 0.0f;
            float v1 = (k0i + 1 < kvalid) ? W[(size_t)(k0i + 1) * 128 + nn] : 0.0f;
            p[w] = (unsigned)f2bf(v0) | ((unsigned)f2bf(v1) << 16);
        }
    } else {
        const int ks = f - 48;
        const int kb = ks * 32 + ((l >> 4) << 3);
        #pragma unroll
        for (int w = 0; w < 4; ++w) {
            int k0i = kb + 2 * w;
            float v0 = (n < 3) ? w2[(size_t)k0i * 3 + n]       : 0.0f;
            float v1 = (n < 3) ? w2[(size_t)(k0i + 1) * 3 + n] : 0.0f;
            p[w] = (unsigned)f2bf(v0) | ((unsigned)f2bf(v1) << 16);
        }
    }
    wsB[f * 64 + l] = make_uint4(p[0], p[1], p[2], p[3]);
}

// ------- fused v11 = r10 + L2-as-MFMA + cvt_pk/rcp VALU diet -------
__global__ __launch_bounds__(256, 2)
void mpi_v11(const float* __restrict__ rays_o,
             const float* __restrict__ rays_d,
             const float* __restrict__ dgrid,   // (256,256,128,1)
             const float* __restrict__ k0g,     // (256,256,128,12)
             const float* __restrict__ ash,     // (128,)
             const float* __restrict__ w0,      // rows 39..65 used here
             const float* __restrict__ b0,
             const float* __restrict__ b1,
             const float* __restrict__ b2,
             const uint4* __restrict__ wsB,
             float* __restrict__ out)           // (8192,3)
{
    // per-wave slab: 4096 shorts (8 KB), overlaying
    //  phase A (sA): row i (0..31) at i*56; guard zeros at 1792..1799
    //  phase B (sH): row i at i*128, elem ^ ((i&7)<<3)  (h0, then h1)
    // all slab traffic wave-private -> transitions are wave-local lgkmcnt drains.
    __shared__ __align__(16) unsigned short slab[4][4096];
    __shared__ float s_scan[128], s_wgt[128], s_rayh[128];
    __shared__ float s_part[4][3];
    __shared__ float s_alast;

    const int t = threadIdx.x;
    const int lane = t & 63;
    const int wv   = t >> 6;
    const int kgrp = lane >> 4;
    const int colb = lane & 15;
    const int p    = t >> 1;      // point 0..127
    const int pr   = p & 31;      // row within wave slab
    const int half = t & 1;       // x-corner (ix / ix+1)
    const int r    = blockIdx.x;

    unsigned short* sw = &slab[wv][0];
    if (lane == 0) *(uint4*)&sw[1792] = make_uint4(0u, 0u, 0u, 0u);  // guard

    const float ox = rays_o[3*r+0], oy = rays_o[3*r+1], oz = rays_o[3*r+2];
    const float dxr = rays_d[3*r+0], dyr = rays_d[3*r+1], dzr = rays_d[3*r+2];

    // ---- gather: 2 threads/point, 2 corners each (y, y+1) on plane izn ----
    const float tp = (float)p * (1.0f/127.0f);
    const float px = fmaf(dxr, tp, ox);
    const float py = fmaf(dyr, tp, oy);
    const float pz = fmaf(dzr, tp, oz);
    float ux = fminf(fmaxf((px + 1.0f) * 127.5f, 0.0f), 255.0f);
    float uy = fminf(fmaxf((py + 1.0f) * 127.5f, 0.0f), 255.0f);
    float uz = fminf(fmaxf(pz * 127.0f, 0.0f), 127.0f);
    int ix = (int)ux; if (ix > 254) ix = 254;
    int iy = (int)uy; if (iy > 254) iy = 254;
    const int izn = (int)(uz + 0.5f);          // z-snap (oz=0,dz=1: uz = p +- 1.5e-5)
    const float fx = ux - (float)ix;
    const float fy = uy - (float)iy;
    const float wxh = half ? fx : 1.0f - fx;
    const float cwa = wxh * (1.0f - fy);       // (y)   corner weight
    const float cwb = wxh * fy;                // (y+1) corner weight
    const int bi = ((ix + half)*256 + iy)*128 + izn;
    {
        const float* g0 = k0g + (size_t)bi * 12;          // (y,   izn)
        const float* g2 = k0g + (size_t)(bi + 128) * 12;  // (y+1, izn)
        float4 L[6];
        L[0]=((const float4*)g0)[0]; L[1]=((const float4*)g0)[1]; L[2]=((const float4*)g0)[2];
        L[3]=((const float4*)g2)[0]; L[4]=((const float4*)g2)[1]; L[5]=((const float4*)g2)[2];
        const float dga = dgrid[bi], dgb = dgrid[bi + 128];

        float f[13];
        f[0]=cwa*L[0].x; f[1]=cwa*L[0].y; f[2]=cwa*L[0].z; f[3]=cwa*L[0].w;
        f[4]=cwa*L[1].x; f[5]=cwa*L[1].y; f[6]=cwa*L[1].z; f[7]=cwa*L[1].w;
        f[8]=cwa*L[2].x; f[9]=cwa*L[2].y; f[10]=cwa*L[2].z; f[11]=cwa*L[2].w;
        f[12]=cwa*dga;
        f[0]=fmaf(cwb,L[3].x,f[0]);  f[1]=fmaf(cwb,L[3].y,f[1]);
        f[2]=fmaf(cwb,L[3].z,f[2]);  f[3]=fmaf(cwb,L[3].w,f[3]);
        f[4]=fmaf(cwb,L[4].x,f[4]);  f[5]=fmaf(cwb,L[4].y,f[5]);
        f[6]=fmaf(cwb,L[4].z,f[6]);  f[7]=fmaf(cwb,L[4].w,f[7]);
        f[8]=fmaf(cwb,L[5].x,f[8]);  f[9]=fmaf(cwb,L[5].y,f[9]);
        f[10]=fmaf(cwb,L[5].z,f[10]); f[11]=fmaf(cwb,L[5].w,f[11]);
        f[12]=fmaf(cwb,dgb,f[12]);
        #pragma unroll
        for (int q = 0; q < 13; ++q) f[q] += __shfl_xor(f[q], 1);

        if (half == 0) {
            #pragma unroll
            for (int q = 0; q < 6; ++q)
                *(unsigned*)&sw[pr*56 + 2*q] = cvtpk(f[2*q], f[2*q+1]);
            const float dsh = f[12] + ash[izn];
            const float sp  = fmaxf(dsh, 0.0f) + __logf(1.0f + __expf(-fabsf(dsh)));
            const float alpha = 1.0f - __expf(-2.0f * sp);   // INTERVAL = 2
            s_scan[p] = 1.0f - alpha;
        } else {
            // xemb via double-angle: sin/cos(x*2^f) from one sin/cos per coord
            float e[28];
            e[0]=px; e[1]=py; e[2]=pz;
            const float pc[3] = {px, py, pz};
            #pragma unroll
            for (int c = 0; c < 3; ++c) {
                float s = __sinf(pc[c]), cc = __cosf(pc[c]);
                e[3  + c*4] = s;
                e[15 + c*4] = cc;
                #pragma unroll
                for (int fq = 1; fq < 4; ++fq) {
                    const float ns = (s + s) * cc;
                    const float nc = fmaf(-2.0f * s, s, 1.0f);
                    s = ns; cc = nc;
                    e[3  + c*4 + fq] = s;
                    e[15 + c*4 + fq] = cc;
                }
            }
            e[27] = 0.0f;
            #pragma unroll
            for (int q = 0; q < 14; ++q)
                *(unsigned*)&sw[pr*56 + 12 + 2*q] = cvtpk(e[2*q], e[2*q+1]); // cols 12..39
            #pragma unroll
            for (int q = 20; q < 28; ++q)
                *(unsigned*)&sw[pr*56 + 2*q] = 0u;                            // cols 40..55
        }
    }
    __syncthreads();   // B1: s_scan (cross-wave) + sA complete

    // ---- wave0: shuffle cumprod scan; waves 2-3: vemb fold ----
    if (t < 64) {
        const float v0r = s_scan[t], v1r = s_scan[t+64];
        float v0 = v0r, v1 = v1r;
        #pragma unroll
        for (int off = 1; off < 64; off <<= 1) {
            const float u = __shfl_up(v0, off); if (lane >= off) v0 *= u;
        }
        const float tot = __shfl(v0, 63);
        #pragma unroll
        for (int off = 1; off < 64; off <<= 1) {
            const float u = __shfl_up(v1, off); if (lane >= off) v1 *= u;
        }
        v1 *= tot;
        float ex0 = __shfl_up(v0, 1); if (t == 0) ex0 = 1.0f;
        float ex1 = __shfl_up(v1, 1); if (t == 0) ex1 = tot;
        s_wgt[t]    = (1.0f - v0r) * ex0;
        s_wgt[t+64] = (1.0f - v1r) * ex1;
        if (t == 63) s_alast = v1;
    } else if (t >= 128) {
        const int n = t - 128;
        const float inv = rsqrtf(dxr*dxr + dyr*dyr + dzr*dzr);
        const float vx = dxr*inv, vy = dyr*inv, vz = dzr*inv;
        float ve[27];
        ve[0]=vx; ve[1]=vy; ve[2]=vz;
        const float vc[3] = {vx, vy, vz};
        #pragma unroll
        for (int c = 0; c < 3; ++c) {
            float s = __sinf(vc[c]), cc = __cosf(vc[c]);
            ve[3  + c*4] = s;
            ve[15 + c*4] = cc;
            #pragma unroll
            for (int fq = 1; fq < 4; ++fq) {
                const float ns = (s + s) * cc;
                const float nc = fmaf(-2.0f * s, s, 1.0f);
                s = ns; cc = nc;
                ve[3  + c*4 + fq] = s;
                ve[15 + c*4 + fq] = cc;
            }
        }
        float acc = b0[n];
        #pragma unroll
        for (int i = 0; i < 27; ++i)
            acc = fmaf(ve[i], w0[(size_t)(39 + i) * 128 + n], acc);
        s_rayh[n] = acc;
    }
    __syncthreads();   // B2: s_wgt/s_rayh complete

    // ---- L0: sA(32x64-pad per wave) @ w0T -> C0 ----
    f32x4 C0[2][8];
    #pragma unroll
    for (int mt = 0; mt < 2; ++mt)
        #pragma unroll
        for (int nt = 0; nt < 8; ++nt) C0[mt][nt] = (f32x4){0.f,0.f,0.f,0.f};

    #pragma unroll
    for (int ks = 0; ks < 2; ++ks) {
        bf16x8 B[8];
        #pragma unroll
        for (int nt = 0; nt < 8; ++nt) {
            uint4 raw = wsB[(ks*8 + nt) * 64 + lane];
            B[nt] = *(bf16x8*)&raw;
        }
        bf16x8 A[2];
        #pragma unroll
        for (int mt = 0; mt < 2; ++mt)
            A[mt] = *(const bf16x8*)&sw[(mt*16 + colb)*56 + ks*32 + kgrp*8];
        #pragma unroll
        for (int mt = 0; mt < 2; ++mt)
            #pragma unroll
            for (int nt = 0; nt < 8; ++nt)
                C0[mt][nt] = __builtin_amdgcn_mfma_f32_16x16x32_bf16(A[mt], B[nt], C0[mt][nt], 0,0,0);
    }

    // ---- sA dead; drain reads, then h0 = relu(C0+rayh) -> same slab (sH) ----
    __asm__ volatile("s_waitcnt lgkmcnt(0)" ::: "memory");
    __builtin_amdgcn_sched_barrier(0);
    {
        float rh[8];
        #pragma unroll
        for (int nt = 0; nt < 8; ++nt) rh[nt] = s_rayh[nt*16 + colb];
        #pragma unroll
        for (int mt = 0; mt < 2; ++mt)
            #pragma unroll
            for (int nt = 0; nt < 8; ++nt)
                #pragma unroll
                for (int rg = 0; rg < 4; ++rg) {
                    const int row32 = mt*16 + kgrp*4 + rg;
                    const float v = fmaxf(C0[mt][nt][rg] + rh[nt], 0.0f);
                    const int elem = (nt*16 + colb) ^ ((row32 & 7) << 3);
                    sw[row32*128 + elem] = f2bf(v);
                }
    }
    __asm__ volatile("s_waitcnt lgkmcnt(0)" ::: "memory");
    __builtin_amdgcn_sched_barrier(0);

    // ---- L1: h0(32x128 per wave) @ w1T -> C1 ----
    f32x4 C1[2][8];
    #pragma unroll
    for (int mt = 0; mt < 2; ++mt)
        #pragma unroll
        for (int nt = 0; nt < 8; ++nt) C1[mt][nt] = (f32x4){0.f,0.f,0.f,0.f};

    #pragma unroll
    for (int ks = 0; ks < 4; ++ks) {
        bf16x8 B[8];
        #pragma unroll
        for (int nt = 0; nt < 8; ++nt) {
            uint4 raw = wsB[(16 + ks*8 + nt) * 64 + lane];
            B[nt] = *(bf16x8*)&raw;
        }
        bf16x8 A[2];
        #pragma unroll
        for (int mt = 0; mt < 2; ++mt) {
            const int row32 = mt*16 + colb;
            const int elem = (ks*32 + kgrp*8) ^ ((row32 & 7) << 3);
            A[mt] = *(const bf16x8*)&sw[row32*128 + elem];
        }
        #pragma unroll
        for (int mt = 0; mt < 2; ++mt)
            #pragma unroll
            for (int nt = 0; nt < 8; ++nt)
                C1[mt][nt] = __builtin_amdgcn_mfma_f32_16x16x32_bf16(A[mt], B[nt], C1[mt][nt], 0,0,0);
    }

    // ---- h1 = relu(C1 + b1) -> slab (same swizzled layout); C1 dies ----
    __asm__ volatile("s_waitcnt lgkmcnt(0)" ::: "memory");
    __builtin_amdgcn_sched_barrier(0);
    {
        float bb[8];
        #pragma unroll
        for (int nt = 0; nt < 8; ++nt) bb[nt] = b1[nt*16 + colb];
        #pragma unroll
        for (int mt = 0; mt < 2; ++mt)
            #pragma unroll
            for (int nt = 0; nt < 8; ++nt)
                #pragma unroll
                for (int rg = 0; rg < 4; ++rg) {
                    const int row32 = mt*16 + kgrp*4 + rg;
                    const float v = fmaxf(C1[mt][nt][rg] + bb[nt], 0.0f);
                    const int elem = (nt*16 + colb) ^ ((row32 & 7) << 3);
                    sw[row32*128 + elem] = f2bf(v);
                }
    }
    __asm__ volatile("s_waitcnt lgkmcnt(0)" ::: "memory");
    __builtin_amdgcn_sched_barrier(0);

    // ---- L2 as MFMA: h1(32x128) @ w2T(16-col tile, cols>=3 zero) -> C2 ----
    f32x4 C2[2];
    C2[0] = (f32x4){0.f,0.f,0.f,0.f};
    C2[1] = (f32x4){0.f,0.f,0.f,0.f};
    #pragma unroll
    for (int ks = 0; ks < 4; ++ks) {
        uint4 raw = wsB[(48 + ks) * 64 + lane];
        const bf16x8 B2v = *(bf16x8*)&raw;
        #pragma unroll
        for (int mt = 0; mt < 2; ++mt) {
            const int row32 = mt*16 + colb;
            const int elem = (ks*32 + kgrp*8) ^ ((row32 & 7) << 3);
            const bf16x8 A = *(const bf16x8*)&sw[row32*128 + elem];
            C2[mt] = __builtin_amdgcn_mfma_f32_16x16x32_bf16(A, B2v, C2[mt], 0,0,0);
        }
    }

    // ---- epilogue: sigmoid + composite; C2 lane holds rows kgrp*4+rg, col colb ----
    {
        const float wb = (colb < 3) ? b2[colb] : 0.0f;
        float acc = 0.0f;
        #pragma unroll
        for (int mt = 0; mt < 2; ++mt)
            #pragma unroll
            for (int rg = 0; rg < 4; ++rg) {
                const int row = wv*32 + mt*16 + kgrp*4 + rg;
                const float o = C2[mt][rg] + wb;
                const float sg = fastrcp(1.0f + __expf(-o));
                acc = fmaf(s_wgt[row], sg, acc);
            }
        if (colb >= 3) acc = 0.0f;
        acc += __shfl_xor(acc, 16);
        acc += __shfl_xor(acc, 32);
        if (lane < 3) s_part[wv][lane] = acc;
    }
    __syncthreads();   // B3
    if (t == 0) {
        const float al = s_alast;
        out[3*r+0] = s_part[0][0] + s_part[1][0] + s_part[2][0] + s_part[3][0] + al;
        out[3*r+1] = s_part[0][1] + s_part[1][1] + s_part[2][1] + s_part[3][1] + al;
        out[3*r+2] = s_part[0][2] + s_part[1][2] + s_part[2][2] + s_part[3][2] + al;
    }
}

extern "C" void kernel_launch(void* const* d_in, const int* in_sizes, int n_in,
                              void* d_out, int out_size, void* d_ws, size_t ws_size,
                              hipStream_t stream) {
    const float* rays_o = (const float*)d_in[0];
    const float* rays_d = (const float*)d_in[1];
    const float* dgrid  = (const float*)d_in[2];
    const float* k0g    = (const float*)d_in[3];
    const float* ash    = (const float*)d_in[4];
    const float* w0     = (const float*)d_in[5];
    const float* b0     = (const float*)d_in[6];
    const float* w1     = (const float*)d_in[7];
    const float* b1     = (const float*)d_in[8];
    const float* w2     = (const float*)d_in[9];
    const float* b2     = (const float*)d_in[10];
    float* out = (float*)d_out;
    uint4* wsB = (uint4*)d_ws;   // 52*64*16 = 53248 B

    prep_weights<<<52, 64, 0, stream>>>(w0, w1, w2, wsB);
    mpi_v11<<<NRAYS, 256, 0, stream>>>(rays_o, rays_d, dgrid, k0g, ash,
                                       w0, b0, b1, b2, wsB, out);
}

// Round 12
// 139.236 us; speedup vs baseline: 1.1461x; 1.1461x over previous
//
#include <hip/hip_runtime.h>
#include <math.h>

#define NRAYS 8192

typedef short bf16x8 __attribute__((ext_vector_type(8)));
typedef float f32x4  __attribute__((ext_vector_type(4)));

__device__ __host__ __forceinline__ unsigned short f2bf(float f) {
    union { float f; unsigned u; } v; v.f = f;
    unsigned r = v.u + 0x7FFFu + ((v.u >> 16) & 1u);
    return (unsigned short)(r >> 16);
}
__device__ __forceinline__ unsigned pack2(float a, float b) {
    return (unsigned)f2bf(a) | ((unsigned)f2bf(b) << 16);
}
__device__ __forceinline__ float fastrcp(float x) {
    float r;
    __asm__("v_rcp_f32 %0, %1" : "=v"(r) : "v"(x));
    return r;
}

// ---------------- prep: pack w0/w1 into MFMA B-fragment order ----------------
// Frag f<16: L0 (ks=f>>3, nt=f&7), K=64, rows>=39 zero. f>=16: L1.
// Lane l holds B[k=(l>>4)*8+j][n=nt*16+(l&15)], 8 bf16 = 16 B.
__global__ void prep_weights(const float* __restrict__ w0,
                             const float* __restrict__ w1,
                             uint4* __restrict__ wsB)
{
    const int f = blockIdx.x;   // 0..47
    const int l = threadIdx.x;  // 0..63
    const float* W; int kvalid, ks, nt;
    if (f < 16) { ks = f >> 3; nt = f & 7; W = w0; kvalid = 39; }
    else        { int g = f - 16; ks = g >> 3; nt = g & 7; W = w1; kvalid = 128; }
    const int n  = nt * 16 + (l & 15);
    const int kb = ks * 32 + ((l >> 4) << 3);
    unsigned p[4];
    #pragma unroll
    for (int w = 0; w < 4; ++w) {
        int k0i = kb + 2 * w;
        float v0 = (k0i     < kvalid) ? W[(size_t)k0i * 128 + n]       : 0.0f;
        float v1 = (k0i + 1 < kvalid) ? W[(size_t)(k0i + 1) * 128 + n] : 0.0f;
        p[w] = (unsigned)f2bf(v0) | ((unsigned)f2bf(v1) << 16);
    }
    wsB[f * 64 + l] = make_uint4(p[0], p[1], p[2], p[3]);
}

// ------- fused v12 = r10 (measured best, 145.9 us) + rcp sigmoid -------
// 1 ray/block, 256 thr, ~34.5 KB LDS -> 4 blk/CU. r11's cvt_pk inline asm and
// L2-as-MFMA both reverted (regressed to 159.6: m240 warning was right, and
// lengthening the serial chain with LDS round-trips loses even when MFMA idles).
__global__ __launch_bounds__(256, 2)
void mpi_v12(const float* __restrict__ rays_o,
             const float* __restrict__ rays_d,
             const float* __restrict__ dgrid,   // (256,256,128,1)
             const float* __restrict__ k0g,     // (256,256,128,12)
             const float* __restrict__ ash,     // (128,)
             const float* __restrict__ w0,      // rows 39..65 used here
             const float* __restrict__ b0,
             const float* __restrict__ b1,
             const float* __restrict__ w2,      // (128,3)
             const float* __restrict__ b2,
             const uint4* __restrict__ wsB,
             float* __restrict__ out)           // (8192,3)
{
    // per-wave slab: 4096 shorts (8 KB), overlaying
    //  phase A (sA): row i (0..31) at i*56; guard zeros at 1792..1799
    //  phase B (sH): row i at i*128, elem ^ ((i&7)<<3)
    // all slab traffic wave-private -> sA->sH transition = wave-local lgkmcnt.
    __shared__ __align__(16) unsigned short slab[4][4096];
    __shared__ float s_scan[128], s_wgt[128], s_rayh[128];
    __shared__ float s_part[4][3];
    __shared__ float s_alast;

    const int t = threadIdx.x;
    const int lane = t & 63;
    const int wv   = t >> 6;
    const int kgrp = lane >> 4;
    const int colb = lane & 15;
    const int p    = t >> 1;      // point 0..127
    const int pr   = p & 31;      // row within wave slab
    const int half = t & 1;       // x-corner (ix / ix+1)
    const int r    = blockIdx.x;

    unsigned short* sw = &slab[wv][0];
    if (lane == 0) *(uint4*)&sw[1792] = make_uint4(0u, 0u, 0u, 0u);  // guard

    const float ox = rays_o[3*r+0], oy = rays_o[3*r+1], oz = rays_o[3*r+2];
    const float dxr = rays_d[3*r+0], dyr = rays_d[3*r+1], dzr = rays_d[3*r+2];

    // ---- gather: 2 threads/point, 2 corners each (y, y+1) on plane izn ----
    const float tp = (float)p * (1.0f/127.0f);
    const float px = fmaf(dxr, tp, ox);
    const float py = fmaf(dyr, tp, oy);
    const float pz = fmaf(dzr, tp, oz);
    float ux = fminf(fmaxf((px + 1.0f) * 127.5f, 0.0f), 255.0f);
    float uy = fminf(fmaxf((py + 1.0f) * 127.5f, 0.0f), 255.0f);
    float uz = fminf(fmaxf(pz * 127.0f, 0.0f), 127.0f);
    int ix = (int)ux; if (ix > 254) ix = 254;
    int iy = (int)uy; if (iy > 254) iy = 254;
    const int izn = (int)(uz + 0.5f);          // z-snap (oz=0,dz=1: uz = p +- 1.5e-5)
    const float fx = ux - (float)ix;
    const float fy = uy - (float)iy;
    const float wxh = half ? fx : 1.0f - fx;
    const float cwa = wxh * (1.0f - fy);       // (y)   corner weight
    const float cwb = wxh * fy;                // (y+1) corner weight
    const int bi = ((ix + half)*256 + iy)*128 + izn;
    {
        const float* g0 = k0g + (size_t)bi * 12;          // (y,   izn)
        const float* g2 = k0g + (size_t)(bi + 128) * 12;  // (y+1, izn)
        float4 L[6];
        L[0]=((const float4*)g0)[0]; L[1]=((const float4*)g0)[1]; L[2]=((const float4*)g0)[2];
        L[3]=((const float4*)g2)[0]; L[4]=((const float4*)g2)[1]; L[5]=((const float4*)g2)[2];
        const float dga = dgrid[bi], dgb = dgrid[bi + 128];

        float f[13];
        f[0]=cwa*L[0].x; f[1]=cwa*L[0].y; f[2]=cwa*L[0].z; f[3]=cwa*L[0].w;
        f[4]=cwa*L[1].x; f[5]=cwa*L[1].y; f[6]=cwa*L[1].z; f[7]=cwa*L[1].w;
        f[8]=cwa*L[2].x; f[9]=cwa*L[2].y; f[10]=cwa*L[2].z; f[11]=cwa*L[2].w;
        f[12]=cwa*dga;
        f[0]=fmaf(cwb,L[3].x,f[0]);  f[1]=fmaf(cwb,L[3].y,f[1]);
        f[2]=fmaf(cwb,L[3].z,f[2]);  f[3]=fmaf(cwb,L[3].w,f[3]);
        f[4]=fmaf(cwb,L[4].x,f[4]);  f[5]=fmaf(cwb,L[4].y,f[5]);
        f[6]=fmaf(cwb,L[4].z,f[6]);  f[7]=fmaf(cwb,L[4].w,f[7]);
        f[8]=fmaf(cwb,L[5].x,f[8]);  f[9]=fmaf(cwb,L[5].y,f[9]);
        f[10]=fmaf(cwb,L[5].z,f[10]); f[11]=fmaf(cwb,L[5].w,f[11]);
        f[12]=fmaf(cwb,dgb,f[12]);
        #pragma unroll
        for (int q = 0; q < 13; ++q) f[q] += __shfl_xor(f[q], 1);

        if (half == 0) {
            #pragma unroll
            for (int q = 0; q < 6; ++q)
                *(unsigned*)&sw[pr*56 + 2*q] = pack2(f[2*q], f[2*q+1]);
            const float dsh = f[12] + ash[izn];
            const float sp  = fmaxf(dsh, 0.0f) + __logf(1.0f + __expf(-fabsf(dsh)));
            const float alpha = 1.0f - __expf(-2.0f * sp);   // INTERVAL = 2
            s_scan[p] = 1.0f - alpha;
        } else {
            // xemb via double-angle: sin/cos(x*2^f) from one sin/cos per coord
            float e[28];
            e[0]=px; e[1]=py; e[2]=pz;
            const float pc[3] = {px, py, pz};
            #pragma unroll
            for (int c = 0; c < 3; ++c) {
                float s = __sinf(pc[c]), cc = __cosf(pc[c]);
                e[3  + c*4] = s;
                e[15 + c*4] = cc;
                #pragma unroll
                for (int fq = 1; fq < 4; ++fq) {
                    const float ns = (s + s) * cc;
                    const float nc = fmaf(-2.0f * s, s, 1.0f);
                    s = ns; cc = nc;
                    e[3  + c*4 + fq] = s;
                    e[15 + c*4 + fq] = cc;
                }
            }
            e[27] = 0.0f;
            #pragma unroll
            for (int q = 0; q < 14; ++q)
                *(unsigned*)&sw[pr*56 + 12 + 2*q] = pack2(e[2*q], e[2*q+1]); // cols 12..39
            #pragma unroll
            for (int q = 20; q < 28; ++q)
                *(unsigned*)&sw[pr*56 + 2*q] = 0u;                            // cols 40..55
        }
    }
    __syncthreads();   // B1: s_scan (cross-wave) + sA complete

    // ---- wave0: shuffle cumprod scan; waves 2-3: vemb fold ----
    if (t < 64) {
        const float v0r = s_scan[t], v1r = s_scan[t+64];
        float v0 = v0r, v1 = v1r;
        #pragma unroll
        for (int off = 1; off < 64; off <<= 1) {
            const float u = __shfl_up(v0, off); if (lane >= off) v0 *= u;
        }
        const float tot = __shfl(v0, 63);
        #pragma unroll
        for (int off = 1; off < 64; off <<= 1) {
            const float u = __shfl_up(v1, off); if (lane >= off) v1 *= u;
        }
        v1 *= tot;
        float ex0 = __shfl_up(v0, 1); if (t == 0) ex0 = 1.0f;
        float ex1 = __shfl_up(v1, 1); if (t == 0) ex1 = tot;
        s_wgt[t]    = (1.0f - v0r) * ex0;
        s_wgt[t+64] = (1.0f - v1r) * ex1;
        if (t == 63) s_alast = v1;
    } else if (t >= 128) {
        const int n = t - 128;
        const float inv = rsqrtf(dxr*dxr + dyr*dyr + dzr*dzr);
        const float vx = dxr*inv, vy = dyr*inv, vz = dzr*inv;
        float ve[27];
        ve[0]=vx; ve[1]=vy; ve[2]=vz;
        const float vc[3] = {vx, vy, vz};
        #pragma unroll
        for (int c = 0; c < 3; ++c) {
            float s = __sinf(vc[c]), cc = __cosf(vc[c]);
            ve[3  + c*4] = s;
            ve[15 + c*4] = cc;
            #pragma unroll
            for (int fq = 1; fq < 4; ++fq) {
                const float ns = (s + s) * cc;
                const float nc = fmaf(-2.0f * s, s, 1.0f);
                s = ns; cc = nc;
                ve[3  + c*4 + fq] = s;
                ve[15 + c*4 + fq] = cc;
            }
        }
        float acc = b0[n];
        #pragma unroll
        for (int i = 0; i < 27; ++i)
            acc = fmaf(ve[i], w0[(size_t)(39 + i) * 128 + n], acc);
        s_rayh[n] = acc;
    }
    __syncthreads();   // B2: s_wgt/s_rayh complete

    // ---- L0: sA(32x64-pad per wave) @ w0T -> C0 ----
    f32x4 C0[2][8];
    #pragma unroll
    for (int mt = 0; mt < 2; ++mt)
        #pragma unroll
        for (int nt = 0; nt < 8; ++nt) C0[mt][nt] = (f32x4){0.f,0.f,0.f,0.f};

    #pragma unroll
    for (int ks = 0; ks < 2; ++ks) {
        bf16x8 B[8];
        #pragma unroll
        for (int nt = 0; nt < 8; ++nt) {
            uint4 raw = wsB[(ks*8 + nt) * 64 + lane];
            B[nt] = *(bf16x8*)&raw;
        }
        bf16x8 A[2];
        #pragma unroll
        for (int mt = 0; mt < 2; ++mt)
            A[mt] = *(const bf16x8*)&sw[(mt*16 + colb)*56 + ks*32 + kgrp*8];
        #pragma unroll
        for (int mt = 0; mt < 2; ++mt)
            #pragma unroll
            for (int nt = 0; nt < 8; ++nt)
                C0[mt][nt] = __builtin_amdgcn_mfma_f32_16x16x32_bf16(A[mt], B[nt], C0[mt][nt], 0,0,0);
    }

    // ---- sA dead; drain reads, then h0 = relu(C0+rayh) -> same slab (sH) ----
    __asm__ volatile("s_waitcnt lgkmcnt(0)" ::: "memory");
    __builtin_amdgcn_sched_barrier(0);
    {
        float rh[8];
        #pragma unroll
        for (int nt = 0; nt < 8; ++nt) rh[nt] = s_rayh[nt*16 + colb];
        #pragma unroll
        for (int mt = 0; mt < 2; ++mt)
            #pragma unroll
            for (int nt = 0; nt < 8; ++nt)
                #pragma unroll
                for (int rg = 0; rg < 4; ++rg) {
                    const int row32 = mt*16 + kgrp*4 + rg;
                    const float v = fmaxf(C0[mt][nt][rg] + rh[nt], 0.0f);
                    const int elem = (nt*16 + colb) ^ ((row32 & 7) << 3);
                    sw[row32*128 + elem] = f2bf(v);
                }
    }
    __asm__ volatile("s_waitcnt lgkmcnt(0)" ::: "memory");
    __builtin_amdgcn_sched_barrier(0);

    // ---- L1: h0(32x128 per wave) @ w1T -> C1 ----
    f32x4 C1[2][8];
    #pragma unroll
    for (int mt = 0; mt < 2; ++mt)
        #pragma unroll
        for (int nt = 0; nt < 8; ++nt) C1[mt][nt] = (f32x4){0.f,0.f,0.f,0.f};

    #pragma unroll
    for (int ks = 0; ks < 4; ++ks) {
        bf16x8 B[8];
        #pragma unroll
        for (int nt = 0; nt < 8; ++nt) {
            uint4 raw = wsB[(16 + ks*8 + nt) * 64 + lane];
            B[nt] = *(bf16x8*)&raw;
        }
        bf16x8 A[2];
        #pragma unroll
        for (int mt = 0; mt < 2; ++mt) {
            const int row32 = mt*16 + colb;
            const int elem = (ks*32 + kgrp*8) ^ ((row32 & 7) << 3);
            A[mt] = *(const bf16x8*)&sw[row32*128 + elem];
        }
        #pragma unroll
        for (int mt = 0; mt < 2; ++mt)
            #pragma unroll
            for (int nt = 0; nt < 8; ++nt)
                C1[mt][nt] = __builtin_amdgcn_mfma_f32_16x16x32_bf16(A[mt], B[nt], C1[mt][nt], 0,0,0);
    }

    // ---- L2 (128->3) + sigmoid + composite (consts loaded here, post-L1) ----
    {
        float bb[8], w2c0[8], w2c1[8], w2c2[8];
        #pragma unroll
        for (int nt = 0; nt < 8; ++nt) {
            const int col = nt*16 + colb;
            bb[nt]   = b1[col];
            w2c0[nt] = w2[col*3+0];
            w2c1[nt] = w2[col*3+1];
            w2c2[nt] = w2[col*3+2];
        }
        const float bias0 = b2[0], bias1 = b2[1], bias2 = b2[2];
        float c0 = 0.f, c1 = 0.f, c2 = 0.f;
        #pragma unroll
        for (int mt = 0; mt < 2; ++mt)
            #pragma unroll
            for (int rg = 0; rg < 4; ++rg) {
                const int row = wv*32 + mt*16 + kgrp*4 + rg;
                float o0 = 0.f, o1 = 0.f, o2 = 0.f;
                #pragma unroll
                for (int nt = 0; nt < 8; ++nt) {
                    const float h = fmaxf(C1[mt][nt][rg] + bb[nt], 0.0f);
                    o0 = fmaf(h, w2c0[nt], o0);
                    o1 = fmaf(h, w2c1[nt], o1);
                    o2 = fmaf(h, w2c2[nt], o2);
                }
                #pragma unroll
                for (int off = 1; off <= 8; off <<= 1) {
                    o0 += __shfl_xor(o0, off);
                    o1 += __shfl_xor(o1, off);
                    o2 += __shfl_xor(o2, off);
                }
                if (colb == 0) {
                    const float wg = s_wgt[row];
                    c0 = fmaf(wg, fastrcp(1.0f + __expf(-(o0 + bias0))), c0);
                    c1 = fmaf(wg, fastrcp(1.0f + __expf(-(o1 + bias1))), c1);
                    c2 = fmaf(wg, fastrcp(1.0f + __expf(-(o2 + bias2))), c2);
                }
            }
        c0 += __shfl_down(c0, 32); c0 += __shfl_down(c0, 16);
        c1 += __shfl_down(c1, 32); c1 += __shfl_down(c1, 16);
        c2 += __shfl_down(c2, 32); c2 += __shfl_down(c2, 16);
        if (lane == 0) { s_part[wv][0] = c0; s_part[wv][1] = c1; s_part[wv][2] = c2; }
    }
    __syncthreads();   // B3
    if (t == 0) {
        const float al = s_alast;
        out[3*r+0] = s_part[0][0] + s_part[1][0] + s_part[2][0] + s_part[3][0] + al;
        out[3*r+1] = s_part[0][1] + s_part[1][1] + s_part[2][1] + s_part[3][1] + al;
        out[3*r+2] = s_part[0][2] + s_part[1][2] + s_part[2][2] + s_part[3][2] + al;
    }
}

extern "C" void kernel_launch(void* const* d_in, const int* in_sizes, int n_in,
                              void* d_out, int out_size, void* d_ws, size_t ws_size,
                              hipStream_t stream) {
    const float* rays_o = (const float*)d_in[0];
    const float* rays_d = (const float*)d_in[1];
    const float* dgrid  = (const float*)d_in[2];
    const float* k0g    = (const float*)d_in[3];
    const float* ash    = (const float*)d_in[4];
    const float* w0     = (const float*)d_in[5];
    const float* b0     = (const float*)d_in[6];
    const float* w1     = (const float*)d_in[7];
    const float* b1     = (const float*)d_in[8];
    const float* w2     = (const float*)d_in[9];
    const float* b2     = (const float*)d_in[10];
    float* out = (float*)d_out;
    uint4* wsB = (uint4*)d_ws;   // 48*64*16 = 49152 B

    prep_weights<<<48, 64, 0, stream>>>(w0, w1, wsB);
    mpi_v12<<<NRAYS, 256, 0, stream>>>(rays_o, rays_d, dgrid, k0g, ash,
                                       w0, b0, b1, w2, b2, wsB, out);
}

// Round 13
// 137.730 us; speedup vs baseline: 1.1586x; 1.0109x over previous
//
#include <hip/hip_runtime.h>
#include <math.h>

#define NRAYS 8192

typedef short bf16x8 __attribute__((ext_vector_type(8)));
typedef float f32x4  __attribute__((ext_vector_type(4)));

__device__ __host__ __forceinline__ unsigned short f2bf(float f) {
    union { float f; unsigned u; } v; v.f = f;
    unsigned r = v.u + 0x7FFFu + ((v.u >> 16) & 1u);
    return (unsigned short)(r >> 16);
}
__device__ __forceinline__ unsigned pack2(float a, float b) {
    return (unsigned)f2bf(a) | ((unsigned)f2bf(b) << 16);
}
__device__ __forceinline__ float fastrcp(float x) {
    float r;
    __asm__("v_rcp_f32 %0, %1" : "=v"(r) : "v"(x));
    return r;
}

// ---------------- prep: pack w0/w1 into MFMA B-fragment order ----------------
// Frag f<16: L0 (ks=f>>3, nt=f&7), K=64, rows>=39 zero. f>=16: L1.
// Lane l holds B[k=(l>>4)*8+j][n=nt*16+(l&15)], 8 bf16 = 16 B.
// (The same bytes also serve as an A-fragment with row=l&15 — used by the
//  swapped L0 below: A/B index maps are identical for 16x16x32.)
__global__ void prep_weights(const float* __restrict__ w0,
                             const float* __restrict__ w1,
                             uint4* __restrict__ wsB)
{
    const int f = blockIdx.x;   // 0..47
    const int l = threadIdx.x;  // 0..63
    const float* W; int kvalid, ks, nt;
    if (f < 16) { ks = f >> 3; nt = f & 7; W = w0; kvalid = 39; }
    else        { int g = f - 16; ks = g >> 3; nt = g & 7; W = w1; kvalid = 128; }
    const int n  = nt * 16 + (l & 15);
    const int kb = ks * 32 + ((l >> 4) << 3);
    unsigned p[4];
    #pragma unroll
    for (int w = 0; w < 4; ++w) {
        int k0i = kb + 2 * w;
        float v0 = (k0i     < kvalid) ? W[(size_t)k0i * 128 + n]       : 0.0f;
        float v1 = (k0i + 1 < kvalid) ? W[(size_t)(k0i + 1) * 128 + n] : 0.0f;
        p[w] = (unsigned)f2bf(v0) | ((unsigned)f2bf(v1) << 16);
    }
    wsB[f * 64 + l] = make_uint4(p[0], p[1], p[2], p[3]);
}

// ------- fused v13 = r12 + swapped L0 (transposed C0 -> b64 h0 writes) -------
// L0 computed as mfma(A=w0frag, B=featfrag): output C0s rows = h-dim n,
// cols = point. Lane then holds 4 CONSECUTIVE n for one point -> pack pairs,
// 16 ds_write_b64 instead of 64 ds_write_b16 (+64 f2bf). h0 bytes identical.
__global__ __launch_bounds__(256, 2)
void mpi_v13(const float* __restrict__ rays_o,
             const float* __restrict__ rays_d,
             const float* __restrict__ dgrid,   // (256,256,128,1)
             const float* __restrict__ k0g,     // (256,256,128,12)
             const float* __restrict__ ash,     // (128,)
             const float* __restrict__ w0,      // rows 39..65 used here
             const float* __restrict__ b0,
             const float* __restrict__ b1,
             const float* __restrict__ w2,      // (128,3)
             const float* __restrict__ b2,
             const uint4* __restrict__ wsB,
             float* __restrict__ out)           // (8192,3)
{
    // per-wave slab: 4096 shorts (8 KB), overlaying
    //  phase A (sA): row i (0..31) at i*56; guard zeros at 1792..1799
    //  phase B (sH): row i at i*128, elem ^ ((i&7)<<3)
    // all slab traffic wave-private -> sA->sH transition = wave-local lgkmcnt.
    __shared__ __align__(16) unsigned short slab[4][4096];
    __shared__ float s_scan[128], s_wgt[128], s_rayh[128];
    __shared__ float s_part[4][3];
    __shared__ float s_alast;

    const int t = threadIdx.x;
    const int lane = t & 63;
    const int wv   = t >> 6;
    const int kgrp = lane >> 4;
    const int colb = lane & 15;
    const int p    = t >> 1;      // point 0..127
    const int pr   = p & 31;      // row within wave slab
    const int half = t & 1;       // x-corner (ix / ix+1)
    const int r    = blockIdx.x;

    unsigned short* sw = &slab[wv][0];
    if (lane == 0) *(uint4*)&sw[1792] = make_uint4(0u, 0u, 0u, 0u);  // guard

    const float ox = rays_o[3*r+0], oy = rays_o[3*r+1], oz = rays_o[3*r+2];
    const float dxr = rays_d[3*r+0], dyr = rays_d[3*r+1], dzr = rays_d[3*r+2];

    // ---- gather: 2 threads/point, 2 corners each (y, y+1) on plane izn ----
    const float tp = (float)p * (1.0f/127.0f);
    const float px = fmaf(dxr, tp, ox);
    const float py = fmaf(dyr, tp, oy);
    const float pz = fmaf(dzr, tp, oz);
    float ux = fminf(fmaxf((px + 1.0f) * 127.5f, 0.0f), 255.0f);
    float uy = fminf(fmaxf((py + 1.0f) * 127.5f, 0.0f), 255.0f);
    float uz = fminf(fmaxf(pz * 127.0f, 0.0f), 127.0f);
    int ix = (int)ux; if (ix > 254) ix = 254;
    int iy = (int)uy; if (iy > 254) iy = 254;
    const int izn = (int)(uz + 0.5f);          // z-snap (oz=0,dz=1: uz = p +- 1.5e-5)
    const float fx = ux - (float)ix;
    const float fy = uy - (float)iy;
    const float wxh = half ? fx : 1.0f - fx;
    const float cwa = wxh * (1.0f - fy);       // (y)   corner weight
    const float cwb = wxh * fy;                // (y+1) corner weight
    const int bi = ((ix + half)*256 + iy)*128 + izn;
    {
        const float* g0 = k0g + (size_t)bi * 12;          // (y,   izn)
        const float* g2 = k0g + (size_t)(bi + 128) * 12;  // (y+1, izn)
        float4 L[6];
        L[0]=((const float4*)g0)[0]; L[1]=((const float4*)g0)[1]; L[2]=((const float4*)g0)[2];
        L[3]=((const float4*)g2)[0]; L[4]=((const float4*)g2)[1]; L[5]=((const float4*)g2)[2];
        const float dga = dgrid[bi], dgb = dgrid[bi + 128];

        float f[13];
        f[0]=cwa*L[0].x; f[1]=cwa*L[0].y; f[2]=cwa*L[0].z; f[3]=cwa*L[0].w;
        f[4]=cwa*L[1].x; f[5]=cwa*L[1].y; f[6]=cwa*L[1].z; f[7]=cwa*L[1].w;
        f[8]=cwa*L[2].x; f[9]=cwa*L[2].y; f[10]=cwa*L[2].z; f[11]=cwa*L[2].w;
        f[12]=cwa*dga;
        f[0]=fmaf(cwb,L[3].x,f[0]);  f[1]=fmaf(cwb,L[3].y,f[1]);
        f[2]=fmaf(cwb,L[3].z,f[2]);  f[3]=fmaf(cwb,L[3].w,f[3]);
        f[4]=fmaf(cwb,L[4].x,f[4]);  f[5]=fmaf(cwb,L[4].y,f[5]);
        f[6]=fmaf(cwb,L[4].z,f[6]);  f[7]=fmaf(cwb,L[4].w,f[7]);
        f[8]=fmaf(cwb,L[5].x,f[8]);  f[9]=fmaf(cwb,L[5].y,f[9]);
        f[10]=fmaf(cwb,L[5].z,f[10]); f[11]=fmaf(cwb,L[5].w,f[11]);
        f[12]=fmaf(cwb,dgb,f[12]);
        #pragma unroll
        for (int q = 0; q < 13; ++q) f[q] += __shfl_xor(f[q], 1);

        if (half == 0) {
            #pragma unroll
            for (int q = 0; q < 6; ++q)
                *(unsigned*)&sw[pr*56 + 2*q] = pack2(f[2*q], f[2*q+1]);
            const float dsh = f[12] + ash[izn];
            const float sp  = fmaxf(dsh, 0.0f) + __logf(1.0f + __expf(-fabsf(dsh)));
            const float alpha = 1.0f - __expf(-2.0f * sp);   // INTERVAL = 2
            s_scan[p] = 1.0f - alpha;
        } else {
            // xemb via double-angle: sin/cos(x*2^f) from one sin/cos per coord
            float e[28];
            e[0]=px; e[1]=py; e[2]=pz;
            const float pc[3] = {px, py, pz};
            #pragma unroll
            for (int c = 0; c < 3; ++c) {
                float s = __sinf(pc[c]), cc = __cosf(pc[c]);
                e[3  + c*4] = s;
                e[15 + c*4] = cc;
                #pragma unroll
                for (int fq = 1; fq < 4; ++fq) {
                    const float ns = (s + s) * cc;
                    const float nc = fmaf(-2.0f * s, s, 1.0f);
                    s = ns; cc = nc;
                    e[3  + c*4 + fq] = s;
                    e[15 + c*4 + fq] = cc;
                }
            }
            e[27] = 0.0f;
            #pragma unroll
            for (int q = 0; q < 14; ++q)
                *(unsigned*)&sw[pr*56 + 12 + 2*q] = pack2(e[2*q], e[2*q+1]); // cols 12..39
            #pragma unroll
            for (int q = 20; q < 28; ++q)
                *(unsigned*)&sw[pr*56 + 2*q] = 0u;                            // cols 40..55
        }
    }
    __syncthreads();   // B1: s_scan (cross-wave) + sA complete

    // ---- wave0: shuffle cumprod scan; waves 2-3: vemb fold ----
    if (t < 64) {
        const float v0r = s_scan[t], v1r = s_scan[t+64];
        float v0 = v0r, v1 = v1r;
        #pragma unroll
        for (int off = 1; off < 64; off <<= 1) {
            const float u = __shfl_up(v0, off); if (lane >= off) v0 *= u;
        }
        const float tot = __shfl(v0, 63);
        #pragma unroll
        for (int off = 1; off < 64; off <<= 1) {
            const float u = __shfl_up(v1, off); if (lane >= off) v1 *= u;
        }
        v1 *= tot;
        float ex0 = __shfl_up(v0, 1); if (t == 0) ex0 = 1.0f;
        float ex1 = __shfl_up(v1, 1); if (t == 0) ex1 = tot;
        s_wgt[t]    = (1.0f - v0r) * ex0;
        s_wgt[t+64] = (1.0f - v1r) * ex1;
        if (t == 63) s_alast = v1;
    } else if (t >= 128) {
        const int n = t - 128;
        const float inv = rsqrtf(dxr*dxr + dyr*dyr + dzr*dzr);
        const float vx = dxr*inv, vy = dyr*inv, vz = dzr*inv;
        float ve[27];
        ve[0]=vx; ve[1]=vy; ve[2]=vz;
        const float vc[3] = {vx, vy, vz};
        #pragma unroll
        for (int c = 0; c < 3; ++c) {
            float s = __sinf(vc[c]), cc = __cosf(vc[c]);
            ve[3  + c*4] = s;
            ve[15 + c*4] = cc;
            #pragma unroll
            for (int fq = 1; fq < 4; ++fq) {
                const float ns = (s + s) * cc;
                const float nc = fmaf(-2.0f * s, s, 1.0f);
                s = ns; cc = nc;
                ve[3  + c*4 + fq] = s;
                ve[15 + c*4 + fq] = cc;
            }
        }
        float acc = b0[n];
        #pragma unroll
        for (int i = 0; i < 27; ++i)
            acc = fmaf(ve[i], w0[(size_t)(39 + i) * 128 + n], acc);
        s_rayh[n] = acc;
    }
    __syncthreads();   // B2: s_wgt/s_rayh complete

    // ---- L0 SWAPPED: mfma(A=w0frag, B=featfrag) -> C0s rows=n, cols=point ----
    f32x4 C0s[2][8];
    #pragma unroll
    for (int mt = 0; mt < 2; ++mt)
        #pragma unroll
        for (int nt = 0; nt < 8; ++nt) C0s[mt][nt] = (f32x4){0.f,0.f,0.f,0.f};

    #pragma unroll
    for (int ks = 0; ks < 2; ++ks) {
        bf16x8 Wf[8];
        #pragma unroll
        for (int nt = 0; nt < 8; ++nt) {
            uint4 raw = wsB[(ks*8 + nt) * 64 + lane];
            Wf[nt] = *(bf16x8*)&raw;
        }
        bf16x8 Ff[2];
        #pragma unroll
        for (int mt = 0; mt < 2; ++mt)
            Ff[mt] = *(const bf16x8*)&sw[(mt*16 + colb)*56 + ks*32 + kgrp*8];
        #pragma unroll
        for (int mt = 0; mt < 2; ++mt)
            #pragma unroll
            for (int nt = 0; nt < 8; ++nt)
                C0s[mt][nt] = __builtin_amdgcn_mfma_f32_16x16x32_bf16(Wf[nt], Ff[mt], C0s[mt][nt], 0,0,0);
    }

    // ---- sA dead; drain, then h0 = relu(C0s + rayh[n]) -> slab, b64 writes ----
    __asm__ volatile("s_waitcnt lgkmcnt(0)" ::: "memory");
    __builtin_amdgcn_sched_barrier(0);
    {
        f32x4 rh4[8];
        #pragma unroll
        for (int nt = 0; nt < 8; ++nt)
            rh4[nt] = *(const f32x4*)&s_rayh[nt*16 + kgrp*4];
        #pragma unroll
        for (int mt = 0; mt < 2; ++mt) {
            const int point = mt*16 + colb;
            #pragma unroll
            for (int nt = 0; nt < 8; ++nt) {
                const float v0 = fmaxf(C0s[mt][nt][0] + rh4[nt][0], 0.0f);
                const float v1 = fmaxf(C0s[mt][nt][1] + rh4[nt][1], 0.0f);
                const float v2 = fmaxf(C0s[mt][nt][2] + rh4[nt][2], 0.0f);
                const float v3 = fmaxf(C0s[mt][nt][3] + rh4[nt][3], 0.0f);
                const int nb   = nt*16 + kgrp*4;
                const int elem = nb ^ ((point & 7) << 3);   // 4-aligned stays contiguous
                *(uint2*)&sw[point*128 + elem] = make_uint2(pack2(v0, v1), pack2(v2, v3));
            }
        }
    }
    __asm__ volatile("s_waitcnt lgkmcnt(0)" ::: "memory");
    __builtin_amdgcn_sched_barrier(0);

    // ---- L1: h0(32x128 per wave) @ w1T -> C1 (normal orientation) ----
    f32x4 C1[2][8];
    #pragma unroll
    for (int mt = 0; mt < 2; ++mt)
        #pragma unroll
        for (int nt = 0; nt < 8; ++nt) C1[mt][nt] = (f32x4){0.f,0.f,0.f,0.f};

    #pragma unroll
    for (int ks = 0; ks < 4; ++ks) {
        bf16x8 B[8];
        #pragma unroll
        for (int nt = 0; nt < 8; ++nt) {
            uint4 raw = wsB[(16 + ks*8 + nt) * 64 + lane];
            B[nt] = *(bf16x8*)&raw;
        }
        bf16x8 A[2];
        #pragma unroll
        for (int mt = 0; mt < 2; ++mt) {
            const int row32 = mt*16 + colb;
            const int elem = (ks*32 + kgrp*8) ^ ((row32 & 7) << 3);
            A[mt] = *(const bf16x8*)&sw[row32*128 + elem];
        }
        #pragma unroll
        for (int mt = 0; mt < 2; ++mt)
            #pragma unroll
            for (int nt = 0; nt < 8; ++nt)
                C1[mt][nt] = __builtin_amdgcn_mfma_f32_16x16x32_bf16(A[mt], B[nt], C1[mt][nt], 0,0,0);
    }

    // ---- L2 (128->3) + sigmoid + composite (consts loaded here, post-L1) ----
    {
        float bb[8], w2c0[8], w2c1[8], w2c2[8];
        #pragma unroll
        for (int nt = 0; nt < 8; ++nt) {
            const int col = nt*16 + colb;
            bb[nt]   = b1[col];
            w2c0[nt] = w2[col*3+0];
            w2c1[nt] = w2[col*3+1];
            w2c2[nt] = w2[col*3+2];
        }
        const float bias0 = b2[0], bias1 = b2[1], bias2 = b2[2];
        float c0 = 0.f, c1 = 0.f, c2 = 0.f;
        #pragma unroll
        for (int mt = 0; mt < 2; ++mt)
            #pragma unroll
            for (int rg = 0; rg < 4; ++rg) {
                const int row = wv*32 + mt*16 + kgrp*4 + rg;
                float o0 = 0.f, o1 = 0.f, o2 = 0.f;
                #pragma unroll
                for (int nt = 0; nt < 8; ++nt) {
                    const float h = fmaxf(C1[mt][nt][rg] + bb[nt], 0.0f);
                    o0 = fmaf(h, w2c0[nt], o0);
                    o1 = fmaf(h, w2c1[nt], o1);
                    o2 = fmaf(h, w2c2[nt], o2);
                }
                #pragma unroll
                for (int off = 1; off <= 8; off <<= 1) {
                    o0 += __shfl_xor(o0, off);
                    o1 += __shfl_xor(o1, off);
                    o2 += __shfl_xor(o2, off);
                }
                if (colb == 0) {
                    const float wg = s_wgt[row];
                    c0 = fmaf(wg, fastrcp(1.0f + __expf(-(o0 + bias0))), c0);
                    c1 = fmaf(wg, fastrcp(1.0f + __expf(-(o1 + bias1))), c1);
                    c2 = fmaf(wg, fastrcp(1.0f + __expf(-(o2 + bias2))), c2);
                }
            }
        c0 += __shfl_down(c0, 32); c0 += __shfl_down(c0, 16);
        c1 += __shfl_down(c1, 32); c1 += __shfl_down(c1, 16);
        c2 += __shfl_down(c2, 32); c2 += __shfl_down(c2, 16);
        if (lane == 0) { s_part[wv][0] = c0; s_part[wv][1] = c1; s_part[wv][2] = c2; }
    }
    __syncthreads();   // B3
    if (t == 0) {
        const float al = s_alast;
        out[3*r+0] = s_part[0][0] + s_part[1][0] + s_part[2][0] + s_part[3][0] + al;
        out[3*r+1] = s_part[0][1] + s_part[1][1] + s_part[2][1] + s_part[3][1] + al;
        out[3*r+2] = s_part[0][2] + s_part[1][2] + s_part[2][2] + s_part[3][2] + al;
    }
}

extern "C" void kernel_launch(void* const* d_in, const int* in_sizes, int n_in,
                              void* d_out, int out_size, void* d_ws, size_t ws_size,
                              hipStream_t stream) {
    const float* rays_o = (const float*)d_in[0];
    const float* rays_d = (const float*)d_in[1];
    const float* dgrid  = (const float*)d_in[2];
    const float* k0g    = (const float*)d_in[3];
    const float* ash    = (const float*)d_in[4];
    const float* w0     = (const float*)d_in[5];
    const float* b0     = (const float*)d_in[6];
    const float* w1     = (const float*)d_in[7];
    const float* b1     = (const float*)d_in[8];
    const float* w2     = (const float*)d_in[9];
    const float* b2     = (const float*)d_in[10];
    float* out = (float*)d_out;
    uint4* wsB = (uint4*)d_ws;   // 48*64*16 = 49152 B

    prep_weights<<<48, 64, 0, stream>>>(w0, w1, wsB);
    mpi_v13<<<NRAYS, 256, 0, stream>>>(rays_o, rays_d, dgrid, k0g, ash,
                                       w0, b0, b1, w2, b2, wsB, out);
}